// Round 10
// baseline (533.327 us; speedup 1.0000x reference)
//
#include <hip/hip_runtime.h>
#include <hip/hip_fp16.h>

#define NN 100000
#define NE 3200000
#define NG 1024
#define NP 100352            // NN padded to multiple of 256
#define NBUCK 391            // ceil(NN/256) buckets of 256 dst nodes
#define NBLK 256
#define CHUNK ((NE + NBLK - 1) / NBLK)
#define WINCAP 12288
#define BATCH 8              // row-gathers in flight per lane

// native vector type accepted by __builtin_nontemporal_load
typedef unsigned int u32x4 __attribute__((ext_vector_type(4)));

// ---------- fp16 helpers ----------
static __device__ inline void acc8_v4(float* acc, u32x4 u) {
#pragma unroll
    for (int k = 0; k < 4; k++) {
        unsigned int w = u[k];
        __half2 h = *reinterpret_cast<__half2*>(&w);
        float2 f = __half22float2(h);
        acc[2 * k + 0] += f.x;
        acc[2 * k + 1] += f.y;
    }
}
static __device__ inline u32x4 pack8(const float* v) {
    u32x4 u;
    __half2 h0 = __floats2half2_rn(v[0], v[1]);
    __half2 h1 = __floats2half2_rn(v[2], v[3]);
    __half2 h2 = __floats2half2_rn(v[4], v[5]);
    __half2 h3 = __floats2half2_rn(v[6], v[7]);
    u[0] = *reinterpret_cast<unsigned int*>(&h0);
    u[1] = *reinterpret_cast<unsigned int*>(&h1);
    u[2] = *reinterpret_cast<unsigned int*>(&h2);
    u[3] = *reinterpret_cast<unsigned int*>(&h3);
    return u;
}

// ---- k1: per-bucket edge histogram ----
__global__ void hist_buckets(const int* __restrict__ dst, int* __restrict__ bcnt) {
    __shared__ int sm[NBUCK];
    int tid = threadIdx.x;
    for (int i = tid; i < NBUCK; i += 256) sm[i] = 0;
    __syncthreads();
    int s = blockIdx.x * CHUNK, e = min(NE, s + CHUNK);
    for (int i = s + tid; i < e; i += 256)
        atomicAdd(&sm[__builtin_nontemporal_load(&dst[i]) >> 8], 1);
    __syncthreads();
    for (int i = tid; i < NBUCK; i += 256)
        if (sm[i]) atomicAdd(&bcnt[i], sm[i]);
}

// ---- k2: exclusive scan of bucket counts ----
__global__ void scan_buckets(const int* __restrict__ bcnt, int* __restrict__ bbase) {
    __shared__ int tmp[512];
    int tid = threadIdx.x;
    int v = (tid < NBUCK) ? bcnt[tid] : 0;
    tmp[tid] = v;
    __syncthreads();
    for (int off = 1; off < 512; off <<= 1) {
        int t = (tid >= off) ? tmp[tid - off] : 0;
        __syncthreads();
        tmp[tid] += t;
        __syncthreads();
    }
    if (tid < NBUCK) bbase[tid] = tmp[tid] - v;
}

// ---- k3: partition edges into bucket regions, packed (dst&255)<<17 | src ----
__global__ void partition(const int* __restrict__ src, const int* __restrict__ dst,
                          const int* __restrict__ bbase, int* __restrict__ bfill,
                          int* __restrict__ part) {
    __shared__ int smh[NBUCK];
    __shared__ int smc[NBUCK];
    int tid = threadIdx.x;
    for (int i = tid; i < NBUCK; i += 256) smh[i] = 0;
    __syncthreads();
    int s = blockIdx.x * CHUNK, e = min(NE, s + CHUNK);
    for (int i = s + tid; i < e; i += 256)
        atomicAdd(&smh[__builtin_nontemporal_load(&dst[i]) >> 8], 1);
    __syncthreads();
    for (int i = tid; i < NBUCK; i += 256) {
        int c = smh[i];
        smc[i] = c ? (bbase[i] + atomicAdd(&bfill[i], c)) : 0;
    }
    __syncthreads();
    for (int i = s + tid; i < e; i += 256) {
        int d = __builtin_nontemporal_load(&dst[i]);
        int sv = __builtin_nontemporal_load(&src[i]);
        int b = d >> 8;
        int p = atomicAdd(&smc[b], 1);
        part[p] = sv | ((d & 255) << 17);
    }
}

// ---- k4: per-bucket CSR build in LDS; sequential write-out; also computes dis ----
__global__ void build_csr(const int* __restrict__ part, const int* __restrict__ bbase,
                          const int* __restrict__ bcnt, int* __restrict__ cnt,
                          int* __restrict__ offs, float* __restrict__ dis,
                          int* __restrict__ srcs) {
    __shared__ int sm_cnt[256];
    __shared__ int sm_off[256];
    __shared__ int sm_cur[256];
    __shared__ int sm_win[WINCAP];
    int b = blockIdx.x, tid = threadIdx.x;
    int base = bbase[b], m = bcnt[b];
    sm_cnt[tid] = 0;
    __syncthreads();
    for (int i = tid; i < m; i += 256)
        atomicAdd(&sm_cnt[__builtin_nontemporal_load(&part[base + i]) >> 17], 1);
    __syncthreads();
    int v = sm_cnt[tid];
    sm_off[tid] = v;
    __syncthreads();
    for (int off = 1; off < 256; off <<= 1) {
        int t = (tid >= off) ? sm_off[tid - off] : 0;
        __syncthreads();
        sm_off[tid] += t;
        __syncthreads();
    }
    int excl = sm_off[tid] - v;
    int n = b * 256 + tid;
    if (n < NN) {
        cnt[n] = v;
        offs[n] = base + excl;
        dis[n] = rsqrtf((float)v + 1.0f);
    }
    sm_cur[tid] = excl;
    __syncthreads();
    if (m <= WINCAP) {
        for (int i = tid; i < m; i += 256) {
            int p = __builtin_nontemporal_load(&part[base + i]);
            int l = atomicAdd(&sm_cur[p >> 17], 1);
            sm_win[l] = p & 0x1FFFF;
        }
        __syncthreads();
        for (int i = tid; i < m; i += 256) srcs[base + i] = sm_win[i];
    } else {
        for (int i = tid; i < m; i += 256) {
            int p = __builtin_nontemporal_load(&part[base + i]);
            int l = atomicAdd(&sm_cur[p >> 17], 1);
            srcs[base + l] = p & 0x1FFFF;
        }
    }
}

// ---- embed one-hot + transform by Wg0, premultiply dis, fp16 rows (2x u32x4) ----
__global__ void embed_tf0(const int* __restrict__ types, const int* __restrict__ pos,
                          const float* __restrict__ W1, const float* __restrict__ b1,
                          const float* __restrict__ W2, const float* __restrict__ b2,
                          const float* __restrict__ Wg0, const float* __restrict__ dis,
                          u32x4* __restrict__ hs) {
    __shared__ float sW[32 * 16];
    int tid = threadIdx.x;
    sW[tid] = Wg0[tid];
    sW[tid + 256] = Wg0[tid + 256];
    __syncthreads();
    int n = blockIdx.x * 256 + tid;
    if (n >= NN) return;
    int ty = types[n], pp = pos[n];
    float z[32];
#pragma unroll
    for (int j = 0; j < 16; j++) z[j] = W1[ty * 16 + j] + b1[j];
#pragma unroll
    for (int j = 0; j < 16; j++) z[16 + j] = W2[pp * 16 + j] + b2[j];
    float dn = dis[n];
    float hv[16];
#pragma unroll
    for (int j = 0; j < 16; j++) {
        float a = 0.0f;
#pragma unroll
        for (int k = 0; k < 32; k++) a += z[k] * sW[k * 16 + j];
        hv[j] = a * dn;
    }
    hs[(size_t)n * 2 + 0] = pack8(hv);
    hs[(size_t)n * 2 + 1] = pack8(hv + 8);
}

// ---- fused aggregate + (transform | pool): 4 lanes per node, edge-quarter each ----
// Each lane gathers FULL 32B rows (2x dwordx4 nt-loads, same 64B line -> one
// line-miss/edge), nt bypasses L1 (tests the MSHR-bound theory).
// Butterfly over lane bits 0-1 merges the 4 partial sums; all lanes end with full z.
template <int RELU, int FUSE_POOL>
__global__ __launch_bounds__(256, 3)
void agg_tf(const u32x4* __restrict__ hs, const int* __restrict__ srcs,
            const int* __restrict__ offs, const int* __restrict__ cnt,
            const float* __restrict__ dis, const float* __restrict__ bias,
            const float* __restrict__ Wn, u32x4* __restrict__ hs_out,
            const int* __restrict__ batch,
            float* __restrict__ pool, int* __restrict__ gcnt) {
    __shared__ float sW[256];
    int tid = threadIdx.x;
    if (!FUSE_POOL) {
        sW[tid] = Wn[tid];
        __syncthreads();
    }
    int gid = blockIdx.x * 256 + tid;
    int n = gid >> 2;
    int c = gid & 3;
    if (n >= NN) return;
    int beg = offs[n], deg = cnt[n];
    float dn = dis[n];
    int i0 = (deg * c) >> 2;
    int iend = (deg * (c + 1)) >> 2;
    float acc[16];
#pragma unroll
    for (int k = 0; k < 16; k++) acc[k] = 0.f;
    for (int i = i0; i < iend; i += BATCH) {
        u32x4 g0[BATCH], g1[BATCH];
#pragma unroll
        for (int j = 0; j < BATCH; j++) {
            int idx = i + j;
            int s = srcs[beg + idx];          // OOB-safe: ws slack after srcs
            s = (idx < iend) ? s : NN;        // sentinel row is zeroed
            const u32x4* row = &hs[(size_t)s * 2];
            g0[j] = __builtin_nontemporal_load(row);
            g1[j] = __builtin_nontemporal_load(row + 1);
        }
#pragma unroll
        for (int j = 0; j < BATCH; j++) {
            acc8_v4(acc, g0[j]);
            acc8_v4(acc + 8, g1[j]);
        }
    }
    // butterfly-merge the 4 edge-quarters (lane bits 0-1); all lanes get the total
#pragma unroll
    for (int k = 0; k < 16; k++) acc[k] += __shfl_xor(acc[k], 1);
#pragma unroll
    for (int k = 0; k < 16; k++) acc[k] += __shfl_xor(acc[k], 2);
    // self loop (hs = h*dis -> self term dn*hs[n]) + bias (+relu), same in all lanes
    u32x4 s0 = hs[(size_t)n * 2 + 0];
    u32x4 s1 = hs[(size_t)n * 2 + 1];
    acc8_v4(acc, s0);
    acc8_v4(acc + 8, s1);
#pragma unroll
    for (int k = 0; k < 16; k++) {
        acc[k] = fmaf(acc[k], dn, bias[k]);
        if (RELU) acc[k] = fmaxf(acc[k], 0.f);
    }
    if (FUSE_POOL) {
        if (c == 0) {
            float s = 0.f;
#pragma unroll
            for (int k = 0; k < 16; k++) s += acc[k] * Wn[k];
            int g = batch[n];
            atomicAdd(&pool[g], s);
            atomicAdd(&gcnt[g], 1);
        }
    } else {
        if (c < 2) {
            float hv[8];
#pragma unroll
            for (int j = 0; j < 8; j++) hv[j] = 0.f;
#pragma unroll
            for (int k = 0; k < 16; k++) {
                const float* w = &sW[k * 16 + c * 8];
#pragma unroll
                for (int j = 0; j < 8; j++) hv[j] += acc[k] * w[j];
            }
#pragma unroll
            for (int j = 0; j < 8; j++) hv[j] *= dn;
            hs_out[(size_t)n * 2 + c] = pack8(hv);
        }
    }
}

__global__ void finalize(const float* __restrict__ pool, const int* __restrict__ gcnt,
                         const float* __restrict__ bo, float* __restrict__ out) {
    int g = blockIdx.x * 256 + threadIdx.x;
    if (g < NG) {
        float c = fmaxf((float)gcnt[g], 1.0f);
        out[g] = pool[g] / c + bo[0];
    }
}

extern "C" void kernel_launch(void* const* d_in, const int* in_sizes, int n_in,
                              void* d_out, int out_size, void* d_ws, size_t ws_size,
                              hipStream_t stream) {
    const int*   types = (const int*)d_in[0];
    const int*   pos   = (const int*)d_in[1];
    const int*   ei    = (const int*)d_in[2];   // [2, E]: src then dst
    const int*   batch = (const int*)d_in[3];
    const float* W1  = (const float*)d_in[4];
    const float* b1  = (const float*)d_in[5];
    const float* W2  = (const float*)d_in[6];
    const float* b2  = (const float*)d_in[7];
    const float* Wg0 = (const float*)d_in[8];
    const float* bg0 = (const float*)d_in[9];
    const float* Wg1 = (const float*)d_in[10];
    const float* bg1 = (const float*)d_in[11];
    const float* Wg2 = (const float*)d_in[12];
    const float* bg2 = (const float*)d_in[13];
    const float* Wo  = (const float*)d_in[14];
    const float* bo  = (const float*)d_in[15];
    float* out = (float*)d_out;

    const int* esrc = ei;
    const int* edst = ei + NE;

    // ---- workspace layout (ints) ----
    int*   bcnt  = (int*)d_ws;                   // 512  (zeroed)
    int*   bfill = bcnt + 512;                   // 512  (zeroed)
    float* pool  = (float*)(bfill + 512);        // 1024 (zeroed)
    int*   gcnt  = (int*)(pool + NG);            // 1024 (zeroed)
    int*   bbase = gcnt + NG;                    // 512
    int*   cnt   = bbase + 512;                  // NP
    int*   offs  = cnt + NP;                     // NP
    float* dis   = (float*)(offs + NP);          // NP
    int*   srcs  = (int*)(dis + NP);             // NE
    int*   part  = srcs + NE;                    // NE  (hs buffers alias this)
    u32x4* hsA   = (u32x4*)part;                 // NP rows x 32B = 3.2 MB
    u32x4* hsB   = (u32x4*)(part + NE / 2);      // 3.2 MB (part is 12.8 MB)
    (void)ws_size; (void)n_in; (void)in_sizes; (void)out_size;

    (void)hipMemsetAsync(d_ws, 0, (size_t)(1024 + 2 * NG) * sizeof(int), stream);

    const int NB256 = (NN + 255) / 256;          // 391
    const int QB4 = (NN * 4 + 255) / 256;        // 1563

    hist_buckets<<<NBLK, 256, 0, stream>>>(edst, bcnt);
    scan_buckets<<<1, 512, 0, stream>>>(bcnt, bbase);
    partition<<<NBLK, 256, 0, stream>>>(esrc, edst, bbase, bfill, part);
    build_csr<<<NBUCK, 256, 0, stream>>>(part, bbase, bcnt, cnt, offs, dis, srcs);

    // zero the sentinel/pad rows of BOTH hs buffers (aliases dead `part` bytes)
    (void)hipMemsetAsync((char*)hsA + (size_t)NN * 32, 0, (size_t)(NP - NN) * 32, stream);
    (void)hipMemsetAsync((char*)hsB + (size_t)NN * 32, 0, (size_t)(NP - NN) * 32, stream);

    // layer 0 input: hs0 = (z0 @ Wg0) * dis  (fp16)
    embed_tf0<<<NB256, 256, 0, stream>>>(types, pos, W1, b1, W2, b2, Wg0, dis, hsA);
    // layer 0 agg + relu + transform Wg1 -> hs1
    agg_tf<1, 0><<<QB4, 256, 0, stream>>>(hsA, srcs, offs, cnt, dis, bg0, Wg1, hsB,
                                          batch, pool, gcnt);
    // layer 1 agg + relu + transform Wg2 -> hs2
    agg_tf<1, 0><<<QB4, 256, 0, stream>>>(hsB, srcs, offs, cnt, dis, bg1, Wg2, hsA,
                                          batch, pool, gcnt);
    // layer 2 agg (no relu) + Wo dot + pool
    agg_tf<0, 1><<<QB4, 256, 0, stream>>>(hsA, srcs, offs, cnt, dis, bg2, Wo, hsB /*unused*/,
                                          batch, pool, gcnt);

    finalize<<<(NG + 255) / 256, 256, 0, stream>>>(pool, gcnt, bo, out);
}